// Round 2
// baseline (560.957 us; speedup 1.0000x reference)
//
#include <hip/hip_runtime.h>

#define C_IN    256
#define S_CELLS 90
#define A_OUT   2086
#define K_FC    180      // E * S = 2*90
#define K_PAD   192      // K padded to 6*32 for mfma 16x16x32
#define N_PAD   2176     // 17 * 128
#define B_BATCH 4096

typedef __attribute__((ext_vector_type(8))) short short8;   // 8 bf16 = 4 VGPR
typedef __attribute__((ext_vector_type(4))) float floatx4;  // mfma C/D

static __device__ __forceinline__ unsigned short f2bf(float f) {
    // round-to-nearest-even fp32 -> bf16 (inputs are finite)
    unsigned u = __float_as_uint(f);
    return (unsigned short)((u + 0x7FFFu + ((u >> 16) & 1u)) >> 16);
}

// ---------------------------------------------------------------------------
// Kernel A: 1x1 conv + BN + 2-head attention (head_dim=1) + out_proj
//   -> Abf [B, 192] bf16 (j = e*90 + s; j in [180,192) zero pad)
// R5: one wave per batch, float4 loads. A channel PAIR is 180 contiguous
// floats = exactly 45 float4s, so lane l (<45) loads float4 at elem 4l of
// each pair: 16 B/lane fully-coalesced stream (G13 sweet spot), 128 iters.
// Element e=4l+j maps statically to (parity = e>=90, cell = e-90*parity);
// even/odd-channel partial sums are combined via a tiny LDS exchange.
// 256-thread blocks (4 waves = 4 batches), grid 1024 = 4 blocks/CU.
// ---------------------------------------------------------------------------
__global__ __launch_bounds__(256) void front_kernel(
    const float* __restrict__ x,        // [B,256,90]
    const float* __restrict__ conv_w,   // [2,256]
    const float* __restrict__ bn_gamma,
    const float* __restrict__ bn_beta,
    const float* __restrict__ bn_mean,
    const float* __restrict__ bn_var,
    const float* __restrict__ ipw,      // [6,2]
    const float* __restrict__ ipb,      // [6]
    const float* __restrict__ opw,      // [2,2]
    const float* __restrict__ opb,      // [2]
    unsigned short* __restrict__ Abf)   // [B,192] bf16
{
    __shared__ float2 part[4][2 * S_CELLS];   // per-elem (y0,y1) partials
    __shared__ float4 kvs[4][S_CELLS];        // (k0, v0, k1, v1) per cell

    const int wv   = threadIdx.x >> 6;   // wave id = sub-batch 0..3
    const int lane = threadIdx.x & 63;
    const int b    = blockIdx.x * 4 + wv;

    if (lane < 45) {
        const float4* xb4 = reinterpret_cast<const float4*>(
                                x + (size_t)b * (C_IN * S_CELLS)) + lane;
        const float2* w0p = reinterpret_cast<const float2*>(conv_w);         // [128] even/odd pairs
        const float2* w1p = reinterpret_cast<const float2*>(conv_w + C_IN);
        const int e0 = 4 * lane;
        const bool o0 = (e0 + 0) >= S_CELLS;   // parity flags, static per lane
        const bool o1 = (e0 + 1) >= S_CELLS;
        const bool o2 = (e0 + 2) >= S_CELLS;
        const bool o3 = (e0 + 3) >= S_CELLS;

        float a0[4] = {0.f, 0.f, 0.f, 0.f};    // partials for out-ch 0
        float a1[4] = {0.f, 0.f, 0.f, 0.f};    // partials for out-ch 1
        #pragma unroll 4
        for (int cp = 0; cp < C_IN / 2; ++cp) {
            const float4 v  = xb4[cp * 45];    // stride 720 B, contiguous stream
            const float2 w0 = w0p[cp];         // uniform -> scalar loads
            const float2 w1 = w1p[cp];
            a0[0] = fmaf(o0 ? w0.y : w0.x, v.x, a0[0]);
            a1[0] = fmaf(o0 ? w1.y : w1.x, v.x, a1[0]);
            a0[1] = fmaf(o1 ? w0.y : w0.x, v.y, a0[1]);
            a1[1] = fmaf(o1 ? w1.y : w1.x, v.y, a1[1]);
            a0[2] = fmaf(o2 ? w0.y : w0.x, v.z, a0[2]);
            a1[2] = fmaf(o2 ? w1.y : w1.x, v.z, a1[2]);
            a0[3] = fmaf(o3 ? w0.y : w0.x, v.w, a0[3]);
            a1[3] = fmaf(o3 ? w1.y : w1.x, v.w, a1[3]);
        }
        part[wv][e0 + 0] = make_float2(a0[0], a1[0]);
        part[wv][e0 + 1] = make_float2(a0[1], a1[1]);
        part[wv][e0 + 2] = make_float2(a0[2], a1[2]);
        part[wv][e0 + 3] = make_float2(a0[3], a1[3]);
    }
    __syncthreads();

    float qA0 = 0.f, qA1 = 0.f, qB0 = 0.f, qB1 = 0.f;
    const int sA = 2 * lane;             // cells owned for attention phase
    const int sB = 2 * lane + 1;

    if (lane < 45) {
        // combine even-channel (elem s) + odd-channel (elem 90+s) partials
        const float2 peA = part[wv][sA], poA = part[wv][S_CELLS + sA];
        const float2 peB = part[wv][sB], poB = part[wv][S_CELLS + sB];

        const float sc0 = bn_gamma[0] * rsqrtf(bn_var[0] + 1e-5f);
        const float sc1 = bn_gamma[1] * rsqrtf(bn_var[1] + 1e-5f);
        const float sh0 = bn_beta[0] - bn_mean[0] * sc0;
        const float sh1 = bn_beta[1] - bn_mean[1] * sc1;
        const float yA0 = (peA.x + poA.x) * sc0 + sh0;
        const float yA1 = (peA.y + poA.y) * sc1 + sh1;
        const float yB0 = (peB.x + poB.x) * sc0 + sh0;
        const float yB1 = (peB.y + poB.y) * sc1 + sh1;

        qA0 = ipw[0] * yA0 + ipw[1] * yA1 + ipb[0];
        qA1 = ipw[2] * yA0 + ipw[3] * yA1 + ipb[1];
        qB0 = ipw[0] * yB0 + ipw[1] * yB1 + ipb[0];
        qB1 = ipw[2] * yB0 + ipw[3] * yB1 + ipb[1];

        kvs[wv][sA] = make_float4(
            ipw[4] * yA0 + ipw[5]  * yA1 + ipb[2],   // k0
            ipw[8] * yA0 + ipw[9]  * yA1 + ipb[4],   // v0
            ipw[6] * yA0 + ipw[7]  * yA1 + ipb[3],   // k1
            ipw[10]* yA0 + ipw[11] * yA1 + ipb[5]);  // v1
        kvs[wv][sB] = make_float4(
            ipw[4] * yB0 + ipw[5]  * yB1 + ipb[2],
            ipw[8] * yB0 + ipw[9]  * yB1 + ipb[4],
            ipw[6] * yB0 + ipw[7]  * yB1 + ipb[3],
            ipw[10]* yB0 + ipw[11] * yB1 + ipb[5]);
    }
    __syncthreads();

    if (lane < 45) {
        float dA0 = 0.f, nA0 = 0.f, dA1 = 0.f, nA1 = 0.f;
        float dB0 = 0.f, nB0 = 0.f, dB1 = 0.f, nB1 = 0.f;
        #pragma unroll 5
        for (int j = 0; j < S_CELLS; ++j) {
            const float4 kv = kvs[wv][j];     // broadcast read, conflict-free
            float e;
            e = __expf(qA0 * kv.x); dA0 += e; nA0 = fmaf(e, kv.y, nA0);
            e = __expf(qA1 * kv.z); dA1 += e; nA1 = fmaf(e, kv.w, nA1);
            e = __expf(qB0 * kv.x); dB0 += e; nB0 = fmaf(e, kv.y, nB0);
            e = __expf(qB1 * kv.z); dB1 += e; nB1 = fmaf(e, kv.w, nB1);
        }
        const float oA0 = nA0 / dA0, oA1 = nA1 / dA1;
        const float oB0 = nB0 / dB0, oB1 = nB1 / dB1;
        unsigned short* ab = Abf + (size_t)b * K_PAD;
        // cells 2l and 2l+1 are adjacent in both channel rows: pack 2x bf16
        const unsigned r0A = f2bf(opw[0] * oA0 + opw[1] * oA1 + opb[0]);
        const unsigned r0B = f2bf(opw[0] * oB0 + opw[1] * oB1 + opb[0]);
        const unsigned r1A = f2bf(opw[2] * oA0 + opw[3] * oA1 + opb[1]);
        const unsigned r1B = f2bf(opw[2] * oB0 + opw[3] * oB1 + opb[1]);
        *(unsigned*)&ab[sA]           = r0A | (r0B << 16);
        *(unsigned*)&ab[S_CELLS + sA] = r1A | (r1B << 16);
    } else if (lane < 57) {
        // lanes 45..56 zero the K pad (j = 180..191)
        Abf[(size_t)b * K_PAD + 135 + lane] = 0;
    }
}

// ---------------------------------------------------------------------------
// fc_w [2086,180] fp32 -> Wbf [2176,192] bf16, zero-padded rows & K tail.
// (Restored from R0: pre-converting once keeps the convert off the GEMM
// staging critical path; W re-reads in the GEMM are then bf16 int4 loads.)
// ---------------------------------------------------------------------------
__global__ __launch_bounds__(192) void wconv_kernel(
    const float* __restrict__ W, unsigned short* __restrict__ Wbf)
{
    const int n = blockIdx.x;        // 0..2175
    const int k = threadIdx.x;       // 0..191
    unsigned short v = 0;
    if (n < A_OUT && k < K_FC) v = f2bf(W[(size_t)n * K_FC + k]);
    Wbf[(size_t)n * K_PAD + k] = v;
}

// ---------------------------------------------------------------------------
// Kernel B: bf16 MFMA GEMM. out[m][n] = sum_k Abf[m][k]*Wbf[n][k] + bias[n]
// M=4096, N=2176(pad), K=192. R5: BM=64 -> grid 17x64 = 1088 blocks
// (4.25 blocks/CU vs 2.125 before) to shrink the write-bound makespan tail.
// 256 thr = 4 waves in 2x2 of 32x64 wave-tiles; mfma_f32_16x16x32_bf16,
// BK=64 (2 k-steps/stage). LDS rows padded 64->72 bf16 (+16B): stride
// 144 B = 36 banks -> frag reads land 2-way (free, m136) not 16-way.
// ---------------------------------------------------------------------------
#define BM 64
#define BN 128
#define BK 64
#define LDSROW 72

__global__ __launch_bounds__(256) void fc_mfma_kernel(
    const unsigned short* __restrict__ Abf,  // [4096,192] bf16
    const unsigned short* __restrict__ Wbf,  // [2176,192] bf16
    const float* __restrict__ bias,          // [2086]
    float* __restrict__ out)                 // [4096,2086] fp32
{
    __shared__ __align__(16) unsigned short As[BM * LDSROW];
    __shared__ __align__(16) unsigned short Bs[BN * LDSROW];

    const int tid  = threadIdx.x;
    const int lane = tid & 63;
    const int wave = tid >> 6;
    const int wy   = wave >> 1;          // M half (0/1): 32 rows
    const int wx   = wave & 1;           // N half (0/1): 64 cols
    const int lrow = lane & 15;
    const int lk   = (lane >> 4) * 8;    // k-offset within a 32-k step
    const int bm   = blockIdx.y * BM;
    const int bn   = blockIdx.x * BN;

    floatx4 acc[2][4] = {};

    for (int k0 = 0; k0 < K_PAD; k0 += BK) {
        // A: 64 rows x 8 int4 chunks = 512 chunks, 2 per thread
        for (int q = tid; q < BM * 8; q += 256) {
            const int m = q >> 3, c = q & 7;
            *(int4*)&As[m * LDSROW + c * 8] =
                *(const int4*)(Abf + (size_t)(bm + m) * K_PAD + k0 + c * 8);
        }
        // B: 128 rows x 8 int4 chunks = 1024 chunks, 4 per thread
        for (int q = tid; q < BN * 8; q += 256) {
            const int m = q >> 3, c = q & 7;
            *(int4*)&Bs[m * LDSROW + c * 8] =
                *(const int4*)(Wbf + (size_t)(bn + m) * K_PAD + k0 + c * 8);
        }
        __syncthreads();

        #pragma unroll
        for (int ks = 0; ks < 2; ++ks) {
            short8 af[2], bf[4];
            #pragma unroll
            for (int t = 0; t < 2; ++t)
                af[t] = *(const short8*)&As[(wy * 32 + t * 16 + lrow) * LDSROW + ks * 32 + lk];
            #pragma unroll
            for (int t = 0; t < 4; ++t)
                bf[t] = *(const short8*)&Bs[(wx * 64 + t * 16 + lrow) * LDSROW + ks * 32 + lk];
            #pragma unroll
            for (int mt = 0; mt < 2; ++mt)
                #pragma unroll
                for (int nt = 0; nt < 4; ++nt)
                    acc[mt][nt] = __builtin_amdgcn_mfma_f32_16x16x32_bf16(
                        af[mt], bf[nt], acc[mt][nt], 0, 0, 0);
        }
        __syncthreads();
    }

    // epilogue: C/D layout col=lane&15, row=(lane>>4)*4+r  [m89]
    const int ccol = lane & 15;
    const int crow = (lane >> 4) * 4;
    #pragma unroll
    for (int mt = 0; mt < 2; ++mt) {
        #pragma unroll
        for (int nt = 0; nt < 4; ++nt) {
            const int n_out = bn + wx * 64 + nt * 16 + ccol;
            if (n_out >= A_OUT) continue;
            const int m_base = bm + wy * 32 + mt * 16 + crow;
            const float bv = bias[n_out];
            #pragma unroll
            for (int r = 0; r < 4; ++r)
                out[(size_t)(m_base + r) * A_OUT + n_out] = acc[mt][nt][r] + bv;
        }
    }
}

// ---------------------------------------------------------------------------
extern "C" void kernel_launch(void* const* d_in, const int* in_sizes, int n_in,
                              void* d_out, int out_size, void* d_ws, size_t ws_size,
                              hipStream_t stream) {
    const float* x        = (const float*)d_in[0];
    const float* conv_w   = (const float*)d_in[1];
    const float* bn_gamma = (const float*)d_in[2];
    const float* bn_beta  = (const float*)d_in[3];
    const float* bn_mean  = (const float*)d_in[4];
    const float* bn_var   = (const float*)d_in[5];
    const float* ipw      = (const float*)d_in[6];
    const float* ipb      = (const float*)d_in[7];
    const float* opw      = (const float*)d_in[8];
    const float* opb      = (const float*)d_in[9];
    const float* fc_w     = (const float*)d_in[10];
    const float* fc_b     = (const float*)d_in[11];
    float* out = (float*)d_out;

    unsigned short* Abf = (unsigned short*)d_ws;                       // 4096*192*2 = 1.57 MB
    unsigned short* Wbf = (unsigned short*)((char*)d_ws + (size_t)B_BATCH * K_PAD * 2);

    front_kernel<<<dim3(B_BATCH / 4), 256, 0, stream>>>(
        x, conv_w, bn_gamma, bn_beta, bn_mean, bn_var,
        ipw, ipb, opw, opb, Abf);

    wconv_kernel<<<dim3(N_PAD), 192, 0, stream>>>(fc_w, Wbf);

    fc_mfma_kernel<<<dim3(N_PAD / BN, B_BATCH / BM), 256, 0, stream>>>(
        Abf, Wbf, fc_b, out);
}

// Round 3
// 546.806 us; speedup vs baseline: 1.0259x; 1.0259x over previous
//
#include <hip/hip_runtime.h>

#define C_IN    256
#define S_CELLS 90
#define A_OUT   2086
#define K_FC    180      // E * S = 2*90
#define K_PAD   192      // K padded to 6*32 for mfma 16x16x32
#define N_PAD   2176     // 17 * 128
#define B_BATCH 4096
#define FRONT_BLOCKS (B_BATCH / 4)      // 1024
#define WCONV_BLOCKS 34                 // 34 * 64 rows = 2176

typedef __attribute__((ext_vector_type(8))) short short8;   // 8 bf16 = 4 VGPR
typedef __attribute__((ext_vector_type(4))) float floatx4;  // mfma C/D

static __device__ __forceinline__ unsigned short f2bf(float f) {
    // round-to-nearest-even fp32 -> bf16 (inputs are finite)
    unsigned u = __float_as_uint(f);
    return (unsigned short)((u + 0x7FFFu + ((u >> 16) & 1u)) >> 16);
}

// ---------------------------------------------------------------------------
// Kernel A (R0-proven config + fused W-convert):
//   blocks [0, 1024): 1x1 conv + BN + 2-head attention (head_dim=1) +
//     out_proj -> Abf [B,192] bf16 (j = e*90 + s; j in [180,192) zero pad).
//     384 threads; 4 batches per block (96-thread sub-blocks, 90 active).
//     Scalar 4B loads, 90 consecutive lanes/row: measured-best front (R0).
//   blocks [1024, 1058): fc_w [2086,180] fp32 -> Wbf [2176,192] bf16,
//     zero-padded rows & K tail (64 rows per block). Fusing saves a launch.
// ---------------------------------------------------------------------------
__global__ __launch_bounds__(384) void front_kernel(
    const float* __restrict__ x,        // [B,256,90]
    const float* __restrict__ conv_w,   // [2,256]
    const float* __restrict__ bn_gamma,
    const float* __restrict__ bn_beta,
    const float* __restrict__ bn_mean,
    const float* __restrict__ bn_var,
    const float* __restrict__ ipw,      // [6,2]
    const float* __restrict__ ipb,      // [6]
    const float* __restrict__ opw,      // [2,2]
    const float* __restrict__ opb,      // [2]
    const float* __restrict__ W,        // [2086,180] fp32
    unsigned short* __restrict__ Abf,   // [B,192] bf16
    unsigned short* __restrict__ Wbf)   // [2176,192] bf16
{
    __shared__ float4 kvpack[4][S_CELLS];   // (k0, v0, k1, v1) per cell

    if (blockIdx.x >= FRONT_BLOCKS) {
        // ---- W conversion: 64 rows of Wbf per block ----
        const int wb = blockIdx.x - FRONT_BLOCKS;
        const int k  = threadIdx.x % K_PAD;       // 0..191
        const int r0 = threadIdx.x / K_PAD;       // 0..1
        #pragma unroll 8
        for (int i = 0; i < 32; ++i) {
            const int n = wb * 64 + 2 * i + r0;   // 0..2175
            unsigned short v = 0;
            if (n < A_OUT && k < K_FC) v = f2bf(W[(size_t)n * K_FC + k]);
            Wbf[(size_t)n * K_PAD + k] = v;
        }
        return;
    }

    const int sub = threadIdx.x / 96;
    const int s   = threadIdx.x % 96;
    const int b   = blockIdx.x * 4 + sub;

    float q0 = 0.f, q1 = 0.f;

    if (s < S_CELLS) {
        const float* xb = x + (size_t)b * (C_IN * S_CELLS) + s;
        float a0 = 0.f, a1 = 0.f;
        #pragma unroll 16
        for (int c = 0; c < C_IN; ++c) {
            float xv = xb[(size_t)c * S_CELLS];
            a0 = fmaf(conv_w[c], xv, a0);
            a1 = fmaf(conv_w[C_IN + c], xv, a1);
        }
        const float sc0 = bn_gamma[0] * rsqrtf(bn_var[0] + 1e-5f);
        const float sc1 = bn_gamma[1] * rsqrtf(bn_var[1] + 1e-5f);
        const float y0 = a0 * sc0 + (bn_beta[0] - bn_mean[0] * sc0);
        const float y1 = a1 * sc1 + (bn_beta[1] - bn_mean[1] * sc1);
        q0 = ipw[0] * y0 + ipw[1] * y1 + ipb[0];
        q1 = ipw[2] * y0 + ipw[3] * y1 + ipb[1];
        const float k0 = ipw[4] * y0 + ipw[5]  * y1 + ipb[2];
        const float k1 = ipw[6] * y0 + ipw[7]  * y1 + ipb[3];
        const float v0 = ipw[8] * y0 + ipw[9]  * y1 + ipb[4];
        const float v1 = ipw[10]* y0 + ipw[11] * y1 + ipb[5];
        kvpack[sub][s] = make_float4(k0, v0, k1, v1);
    }
    __syncthreads();
    if (s < S_CELLS) {
        float den0 = 0.f, num0 = 0.f, den1 = 0.f, num1 = 0.f;
        #pragma unroll 5
        for (int j = 0; j < S_CELLS; ++j) {
            const float4 kv = kvpack[sub][j];
            const float e0 = __expf(q0 * kv.x);
            const float e1 = __expf(q1 * kv.z);
            den0 += e0; num0 = fmaf(e0, kv.y, num0);
            den1 += e1; num1 = fmaf(e1, kv.w, num1);
        }
        const float o0 = num0 / den0;
        const float o1 = num1 / den1;
        const float r0 = opw[0] * o0 + opw[1] * o1 + opb[0];
        const float r1 = opw[2] * o0 + opw[3] * o1 + opb[1];
        Abf[(size_t)b * K_PAD + s]           = f2bf(r0);
        Abf[(size_t)b * K_PAD + S_CELLS + s] = f2bf(r1);
    } else {
        // threads s=90..95 zero the K pad (j = 180..191)
        Abf[(size_t)b * K_PAD + 180 + (s - S_CELLS)] = 0;
        Abf[(size_t)b * K_PAD + 186 + (s - S_CELLS)] = 0;
    }
}

// ---------------------------------------------------------------------------
// Kernel B: bf16 MFMA GEMM. out[m][n] = sum_k Abf[m][k]*Wbf[n][k] + bias[n]
// M=4096, N=2176(pad), K=192. Block 128x128, 256 thr = 4 waves in 2x2 of
// 64x64 wave-tiles; mfma_f32_16x16x32_bf16, BK=64 (2 k-steps/stage).
// LDS rows padded 64->72 bf16 (+16B): row stride 144 B = 36 banks -> frag
// reads land 2-way (free, m136) instead of 16-way.  (R0-proven config.)
// ---------------------------------------------------------------------------
#define BM 128
#define BN 128
#define BK 64
#define LDSROW 72

__global__ __launch_bounds__(256) void fc_mfma_kernel(
    const unsigned short* __restrict__ Abf,  // [4096,192] bf16
    const unsigned short* __restrict__ Wbf,  // [2176,192] bf16
    const float* __restrict__ bias,          // [2086]
    float* __restrict__ out)                 // [4096,2086] fp32
{
    __shared__ __align__(16) unsigned short As[BM * LDSROW];
    __shared__ __align__(16) unsigned short Bs[BN * LDSROW];

    const int tid  = threadIdx.x;
    const int lane = tid & 63;
    const int wave = tid >> 6;
    const int wy   = wave >> 1;          // M half (0/1)
    const int wx   = wave & 1;           // N half (0/1)
    const int lrow = lane & 15;
    const int lk   = (lane >> 4) * 8;    // k-offset within a 32-k step
    const int bm   = blockIdx.y * BM;
    const int bn   = blockIdx.x * BN;

    floatx4 acc[4][4] = {};

    for (int k0 = 0; k0 < K_PAD; k0 += BK) {
        // stage: 128 rows x 64 bf16 = 128 rows x 8 int4 chunks per operand,
        // 2048 chunks total / 256 threads = 8 per thread
        for (int q = tid; q < BM * 8; q += 256) {
            const int m = q >> 3, c = q & 7;
            *(int4*)&As[m * LDSROW + c * 8] =
                *(const int4*)(Abf + (size_t)(bm + m) * K_PAD + k0 + c * 8);
            *(int4*)&Bs[m * LDSROW + c * 8] =
                *(const int4*)(Wbf + (size_t)(bn + m) * K_PAD + k0 + c * 8);
        }
        __syncthreads();

        #pragma unroll
        for (int ks = 0; ks < 2; ++ks) {
            short8 af[4], bf[4];
            #pragma unroll
            for (int t = 0; t < 4; ++t) {
                af[t] = *(const short8*)&As[(wy * 64 + t * 16 + lrow) * LDSROW + ks * 32 + lk];
                bf[t] = *(const short8*)&Bs[(wx * 64 + t * 16 + lrow) * LDSROW + ks * 32 + lk];
            }
            #pragma unroll
            for (int mt = 0; mt < 4; ++mt)
                #pragma unroll
                for (int nt = 0; nt < 4; ++nt)
                    acc[mt][nt] = __builtin_amdgcn_mfma_f32_16x16x32_bf16(
                        af[mt], bf[nt], acc[mt][nt], 0, 0, 0);
        }
        __syncthreads();
    }

    // epilogue: C/D layout col=lane&15, row=(lane>>4)*4+r  [m89]
    const int ccol = lane & 15;
    const int crow = (lane >> 4) * 4;
    #pragma unroll
    for (int mt = 0; mt < 4; ++mt) {
        #pragma unroll
        for (int nt = 0; nt < 4; ++nt) {
            const int n_out = bn + wx * 64 + nt * 16 + ccol;
            if (n_out >= A_OUT) continue;
            const int m_base = bm + wy * 64 + mt * 16 + crow;
            const float bv = bias[n_out];
            #pragma unroll
            for (int r = 0; r < 4; ++r)
                out[(size_t)(m_base + r) * A_OUT + n_out] = acc[mt][nt][r] + bv;
        }
    }
}

// ---------------------------------------------------------------------------
extern "C" void kernel_launch(void* const* d_in, const int* in_sizes, int n_in,
                              void* d_out, int out_size, void* d_ws, size_t ws_size,
                              hipStream_t stream) {
    const float* x        = (const float*)d_in[0];
    const float* conv_w   = (const float*)d_in[1];
    const float* bn_gamma = (const float*)d_in[2];
    const float* bn_beta  = (const float*)d_in[3];
    const float* bn_mean  = (const float*)d_in[4];
    const float* bn_var   = (const float*)d_in[5];
    const float* ipw      = (const float*)d_in[6];
    const float* ipb      = (const float*)d_in[7];
    const float* opw      = (const float*)d_in[8];
    const float* opb      = (const float*)d_in[9];
    const float* fc_w     = (const float*)d_in[10];
    const float* fc_b     = (const float*)d_in[11];
    float* out = (float*)d_out;

    unsigned short* Abf = (unsigned short*)d_ws;                       // 4096*192*2 = 1.57 MB
    unsigned short* Wbf = (unsigned short*)((char*)d_ws + (size_t)B_BATCH * K_PAD * 2);

    front_kernel<<<dim3(FRONT_BLOCKS + WCONV_BLOCKS), 384, 0, stream>>>(
        x, conv_w, bn_gamma, bn_beta, bn_mean, bn_var,
        ipw, ipb, opw, opb, fc_w, Abf, Wbf);

    fc_mfma_kernel<<<dim3(N_PAD / BN, B_BATCH / BM), 256, 0, stream>>>(
        Abf, Wbf, fc_b, out);
}